// Round 19
// baseline (225.763 us; speedup 1.0000x reference)
//
#include <hip/hip_runtime.h>
#include <math.h>
#include <stdint.h>

// StructuralSparseBlock: gather -> (Dense 128x128 + GELU) x2 -> +residual -> LayerNorm
// B=16384, E=2048, G=32, D=128, L=2, fp32 in/out.
// 2 kernels: (1) fused {W -> bf16 MFMA B-fragment layout} + {gather x into bf16
//                [B,G,D]} in d_ws (fallback: fp32 gather into d_out)
//            (2) barrier-free MFMA dense stack + residual + LayerNorm -> d_out
//
// SESSION NOTES (best banked = R18: total 214.9 us; mfma ~161 us):
//  * Rounds 8-11 failed accuracy (~0.3-0.4) with re-layouted (vectorized)
//    epilogues; mechanism never isolated (5x audit clean). The scalar
//    nt*16+c16 epilogue below is QUARANTINED: do not change its data layout.
//    Bias-in-MFMA-C-init is also unexonerated (in the failure cluster).
//  * Round 13: unifying the two epilogue calls regressed (WRITE 267->339 MB,
//    store write-amplification). Keep per-m-tile epilogue.
//  * Round 14: s_setprio(1) around MFMA loops = +14% (barrier-free waves are
//    phase-staggered -> T5 applies). Keep.
//  * Round 17: blocked intermediate + direct-global A-fragment reads regressed
//    (mfma 161->193 us). Direct-global A-reads dead in BOTH layouts (R7, R17).
//  * Register budget: 64 VGPR + 64 acc AGPR = 128 = exactly the 4-waves/SIMD
//    boundary. Do NOT add any live VGPR (no prefetch arrays, no hoisting).
//  * R19 change: hold setprio(1) across the whole L0-MFMA -> GELU -> L1-MFMA
//    compute region (was: dropped during GELU). Drop to 0 before epilogue.

constexpr int E_DIM = 2048;
constexpr int G_DIM = 32;
constexpr int D_DIM = 128;
constexpr float LN_EPS = 1e-3f;

constexpr int ROWS1 = 4;     // rows per block, gather part of prep
constexpr int BM    = 128;   // rows per block, compute pass (4 waves x 32 rows)
constexpr int AW    = 136;   // strip row stride in shorts (272 B: b128-aligned)
constexpr int WPREP_BLOCKS = 512;

typedef float f32x4  __attribute__((ext_vector_type(4)));
typedef short bf16x8 __attribute__((ext_vector_type(8)));

__device__ __forceinline__ short f2bf(float f) {   // RNE float->bf16 (finite inputs)
    uint32_t u = __builtin_bit_cast(uint32_t, f);
    uint32_t r = (u + 0x7fffu + ((u >> 16) & 1u)) >> 16;
    return (short)r;
}
__device__ __forceinline__ float bf2f(short s) {
    uint32_t u = ((uint32_t)(uint16_t)s) << 16;
    return __builtin_bit_cast(float, u);
}
// tanh-form GELU on HW exp2/rcp: max |diff vs exact| ~3e-3
__device__ __forceinline__ float gelu_fast(float x) {
    const float x2 = x * x;
    const float z  = 2.30220817f * x * fmaf(0.044715f, x2, 1.0f);
    const float e  = __builtin_amdgcn_exp2f(-z);
    return x * __builtin_amdgcn_rcpf(1.0f + e);
}

// ---------------- kernel 1: fused wprep + gather ----------------
template<bool WS>
__global__ __launch_bounds__(256) void ssb_prep_kernel(
    const float* __restrict__ x,
    const int*   __restrict__ idx,
    const float* __restrict__ W,
    short* __restrict__ Wf,
    float* __restrict__ outF,      // used when !WS (fp32 gather into d_out)
    short* __restrict__ outH,      // used when WS  (bf16 gather into d_ws)
    int gatherBlocks)
{
    const int tid = threadIdx.x;

    if ((int)blockIdx.x >= gatherBlocks) {
        // ---- wprep: W[g][l][k][n] fp32 -> bf16 B-fragment layout ----
        // frag: ((gl*8+nt)*4+ks)*512 + lane*8 + j <=> W[ks*32+8*(lane>>4)+j][nt*16+(lane&15)]
        const int t    = (blockIdx.x - gatherBlocks) * 256 + tid;   // 0 .. 131071
        const int lane = t & 63;
        const int ks   = (t >> 6) & 3;
        const int nt   = (t >> 8) & 7;
        const int gl   = t >> 11;                          // 0..63 = g*2+l
        const float* Wl = W + (size_t)gl * D_DIM * D_DIM;
        const int n  = nt * 16 + (lane & 15);
        const int k0 = ks * 32 + ((lane >> 4) << 3);
        short* dst = Wf + (size_t)t * 8;
        #pragma unroll
        for (int j = 0; j < 8; ++j) dst[j] = f2bf(Wl[(size_t)(k0 + j) * D_DIM + n]);
        return;
    }

    // ---- gather: x rows staged in LDS, all 32 groups emitted ----
    __shared__ float sX[ROWS1][E_DIM];     // 32 KB
    const int row0 = blockIdx.x * ROWS1;

    const int4 iv0 = *(const int4*)(idx + (0 * 256 + tid) * 4);
    const int4 iv1 = *(const int4*)(idx + (1 * 256 + tid) * 4);
    const int4 iv2 = *(const int4*)(idx + (2 * 256 + tid) * 4);
    const int4 iv3 = *(const int4*)(idx + (3 * 256 + tid) * 4);

    #pragma unroll
    for (int r = 0; r < ROWS1; ++r) {
        const float4* src = (const float4*)(x + (size_t)(row0 + r) * E_DIM);
        float4* dst = (float4*)sX[r];
        dst[tid]       = src[tid];
        dst[tid + 256] = src[tid + 256];
    }
    __syncthreads();

    #pragma unroll
    for (int r = 0; r < ROWS1; ++r) {
        const size_t base = (size_t)(row0 + r) * G_DIM * D_DIM;
        #pragma unroll
        for (int t = 0; t < 4; ++t) {
            const int4 iv = (t == 0) ? iv0 : (t == 1) ? iv1 : (t == 2) ? iv2 : iv3;
            const int j = (t * 256 + tid) * 4;
            const float v0 = sX[r][iv.x], v1 = sX[r][iv.y];
            const float v2 = sX[r][iv.z], v3 = sX[r][iv.w];
            if (WS) {
                short4 v; v.x = f2bf(v0); v.y = f2bf(v1); v.z = f2bf(v2); v.w = f2bf(v3);
                *(short4*)(outH + base + j) = v;
            } else {
                *(float4*)(outF + base + j) = make_float4(v0, v1, v2, v3);
            }
        }
    }
}

// ---------------- kernel 2: barrier-free MFMA, 32 rows/wave ----------------
template<bool WS>
__global__ __launch_bounds__(256, 4) void ssb_mfma_kernel(
    const short* __restrict__ Wf,
    const short* __restrict__ actH,    // WS: bf16 gathered [B][G][D]
    const float* __restrict__ bias,
    const float* __restrict__ gamma,
    const float* __restrict__ beta,
    float* __restrict__ out)
{
    __shared__ __align__(16) short sAct[4][32 * AW];   // 34.8 KB, wave-private strips

    const int g    = blockIdx.y;
    const int tid  = threadIdx.x;
    const int lane = tid & 63;
    const int wv   = tid >> 6;
    const int q    = lane >> 4;          // quarter 0..3
    const int c16  = lane & 15;
    const size_t rbase = (size_t)blockIdx.x * BM + wv * 32;   // wave's first row
    const size_t rowE  = (size_t)G_DIM * D_DIM;               // 4096 elems per batch row

    short* strip = sAct[wv];

    // ---- phase 0: load own 32-row strip into LDS as bf16 (quarter q loads rows 8q..8q+7) ----
    #pragma unroll
    for (int i = 0; i < 8; ++i) {
        const int rl = 8 * q + i;
        const size_t off = ((rbase + rl) * G_DIM + g) * D_DIM + 8 * c16;
        bf16x8 p;
        if (WS) {
            p = *(const bf16x8*)(actH + off);
        } else {
            const float4* src = (const float4*)(out + off);
            const float4 a0 = src[0], a1 = src[1];
            p[0] = f2bf(a0.x); p[1] = f2bf(a0.y); p[2] = f2bf(a0.z); p[3] = f2bf(a0.w);
            p[4] = f2bf(a1.x); p[5] = f2bf(a1.y); p[6] = f2bf(a1.z); p[7] = f2bf(a1.w);
        }
        *(bf16x8*)(strip + rl * AW + 8 * c16) = p;
    }

    const short* Wg0 = Wf + (size_t)(g * 2 + 0) * (D_DIM * D_DIM);
    const short* Wg1 = Wf + (size_t)(g * 2 + 1) * (D_DIM * D_DIM);

    f32x4 acc0[8], acc1[8];

    // ---- layer 0 (acc zero-init; bias added in GELU writeback) ----
    #pragma unroll
    for (int nt = 0; nt < 8; ++nt) { acc0[nt] = (f32x4){0,0,0,0}; acc1[nt] = (f32x4){0,0,0,0}; }
    __builtin_amdgcn_s_setprio(1);     // held through L0 MFMA + GELU + L1 MFMA
    #pragma unroll
    for (int ks = 0; ks < 4; ++ks) {
        const bf16x8 a0 = *(const bf16x8*)(strip + (     c16) * AW + ks * 32 + q * 8);
        const bf16x8 a1 = *(const bf16x8*)(strip + (16 + c16) * AW + ks * 32 + q * 8);
        #pragma unroll
        for (int nt = 0; nt < 8; ++nt) {
            const bf16x8 bfr = *(const bf16x8*)(Wg0 + (nt * 4 + ks) * 512 + lane * 8);
            acc0[nt] = __builtin_amdgcn_mfma_f32_16x16x32_bf16(a0, bfr, acc0[nt], 0, 0, 0);
            acc1[nt] = __builtin_amdgcn_mfma_f32_16x16x32_bf16(a1, bfr, acc1[nt], 0, 0, 0);
        }
    }

    // ---- GELU(acc + b0) -> own strip (wave-private, no barrier) ----
    {
        const float* bl0 = bias + (g * 2 + 0) * D_DIM;
        #pragma unroll
        for (int nt = 0; nt < 8; ++nt) {
            const float b0 = bl0[nt * 16 + c16];
            #pragma unroll
            for (int j = 0; j < 4; ++j) {
                strip[(     4 * q + j) * AW + nt * 16 + c16] = f2bf(gelu_fast(acc0[nt][j] + b0));
                strip[(16 + 4 * q + j) * AW + nt * 16 + c16] = f2bf(gelu_fast(acc1[nt][j] + b0));
            }
        }
    }

    // ---- layer 1 (acc zero-init; bias added in epilogue) ----
    #pragma unroll
    for (int nt = 0; nt < 8; ++nt) { acc0[nt] = (f32x4){0,0,0,0}; acc1[nt] = (f32x4){0,0,0,0}; }
    #pragma unroll
    for (int ks = 0; ks < 4; ++ks) {
        const bf16x8 a0 = *(const bf16x8*)(strip + (     c16) * AW + ks * 32 + q * 8);
        const bf16x8 a1 = *(const bf16x8*)(strip + (16 + c16) * AW + ks * 32 + q * 8);
        #pragma unroll
        for (int nt = 0; nt < 8; ++nt) {
            const bf16x8 bfr = *(const bf16x8*)(Wg1 + (nt * 4 + ks) * 512 + lane * 8);
            acc0[nt] = __builtin_amdgcn_mfma_f32_16x16x32_bf16(a0, bfr, acc0[nt], 0, 0, 0);
            acc1[nt] = __builtin_amdgcn_mfma_f32_16x16x32_bf16(a1, bfr, acc1[nt], 0, 0, 0);
        }
    }
    __builtin_amdgcn_s_setprio(0);     // epilogue at normal priority

    // ---- epilogue (per m-tile; scalar layout QUARANTINED) ----
    const float* bl1 = bias + (g * 2 + 1) * D_DIM;
    float b1[8], gm[8], bt[8];
    #pragma unroll
    for (int nt = 0; nt < 8; ++nt) {
        b1[nt] = bl1[nt * 16 + c16];
        gm[nt] = gamma[g * D_DIM + nt * 16 + c16];
        bt[nt] = beta [g * D_DIM + nt * 16 + c16];
    }

    auto epilogue = [&](f32x4* acc, int mt) {
        const size_t r0 = (rbase + mt * 16 + 4 * q) * rowE + (size_t)g * D_DIM + c16;
        const short* rp = actH + r0;   // WS residual base (row stride rowE)
        const float* fp = out  + r0;   // !WS residual base
        float s[4] = {0, 0, 0, 0}, s2[4] = {0, 0, 0, 0};
        #pragma unroll
        for (int j = 0; j < 4; ++j) {
            #pragma unroll
            for (int nt = 0; nt < 8; ++nt) {
                const float res = WS ? bf2f(rp[j * 4096 + nt * 16]) : fp[j * 4096 + nt * 16];
                const float v = gelu_fast(acc[nt][j] + b1[nt]) + res;
                acc[nt][j] = v;
                s[j] += v; s2[j] += v * v;
            }
        }
        float mu[4], rs[4];
        #pragma unroll
        for (int j = 0; j < 4; ++j) {
            #pragma unroll
            for (int m = 8; m >= 1; m >>= 1) {
                s[j]  += __shfl_xor(s[j],  m, 64);
                s2[j] += __shfl_xor(s2[j], m, 64);
            }
            mu[j] = s[j] * (1.0f / 128.0f);
            const float var = fmaxf(s2[j] * (1.0f / 128.0f) - mu[j] * mu[j], 0.f);
            rs[j] = rsqrtf(var + LN_EPS);
        }
        float* op = out + r0;
        #pragma unroll
        for (int j = 0; j < 4; ++j) {
            #pragma unroll
            for (int nt = 0; nt < 8; ++nt) {
                op[j * 4096 + nt * 16] = (acc[nt][j] - mu[j]) * rs[j] * gm[nt] + bt[nt];
            }
        }
    };
    epilogue(acc0, 0);
    epilogue(acc1, 1);
}

extern "C" void kernel_launch(void* const* d_in, const int* in_sizes, int n_in,
                              void* d_out, int out_size, void* d_ws, size_t ws_size,
                              hipStream_t stream) {
    const float* x     = (const float*)d_in[0];
    const int*   idx   = (const int*)d_in[1];
    const float* W     = (const float*)d_in[2];
    const float* b     = (const float*)d_in[3];
    const float* gamma = (const float*)d_in[4];
    const float* beta  = (const float*)d_in[5];
    float* out = (float*)d_out;
    short* Wf  = (short*)d_ws;                       // 2 MB bf16 fragment-layout W

    const int B = in_sizes[0] / E_DIM;               // 16384
    const size_t wfElems  = (size_t)G_DIM * 2 * D_DIM * D_DIM;       // 1 Mi shorts
    const size_t actElems = (size_t)B * G_DIM * D_DIM;               // 64 Mi shorts
    const bool useWs = ws_size >= (wfElems + actElems) * sizeof(short);
    short* actH = Wf + wfElems;

    const int gatherBlocks = B / ROWS1;              // 4096

    if (useWs) {
        ssb_prep_kernel<true ><<<dim3(gatherBlocks + WPREP_BLOCKS), 256, 0, stream>>>(
            x, idx, W, Wf, out, actH, gatherBlocks);
        ssb_mfma_kernel<true ><<<dim3(B / BM, G_DIM), 256, 0, stream>>>(
            Wf, actH, b, gamma, beta, out);
    } else {
        ssb_prep_kernel<false><<<dim3(gatherBlocks + WPREP_BLOCKS), 256, 0, stream>>>(
            x, idx, W, Wf, out, actH, gatherBlocks);
        ssb_mfma_kernel<false><<<dim3(B / BM, G_DIM), 256, 0, stream>>>(
            Wf, actH, b, gamma, beta, out);
    }
}

// Round 20
// 214.721 us; speedup vs baseline: 1.0514x; 1.0514x over previous
//
#include <hip/hip_runtime.h>
#include <math.h>
#include <stdint.h>

// StructuralSparseBlock: gather -> (Dense 128x128 + GELU) x2 -> +residual -> LayerNorm
// B=16384, E=2048, G=32, D=128, L=2, fp32 in/out.
// 2 kernels: (1) fused {W -> bf16 MFMA B-fragment layout} + {gather x into bf16
//                [B,G,D]} in d_ws (fallback: fp32 gather into d_out)
//            (2) barrier-free MFMA dense stack + residual + LayerNorm -> d_out
//
// FINAL CONFIG (= R14/R18, best measured: total 214.9 us; mfma ~161 us).
// SESSION NOTES:
//  * Rounds 8-11 failed accuracy (~0.3-0.4) with re-layouted (vectorized)
//    epilogues; mechanism never isolated (5x audit clean). The scalar
//    nt*16+c16 epilogue below is QUARANTINED: do not change its data layout.
//    Bias-in-MFMA-C-init is also unexonerated (in the failure cluster).
//  * Round 13: unifying the two epilogue calls regressed (WRITE 267->339 MB,
//    store write-amplification). Keep per-m-tile epilogue.
//  * Round 14: s_setprio(1) tightly around MFMA loops = +14%. Round 19:
//    extending the span across the GELU section regressed (161->170 us) --
//    the asymmetric MFMA-vs-staging arbitration is the whole benefit.
//    Placement is the measured optimum: none=187, MFMA-only=161, +GELU=170.
//  * Round 17: blocked intermediate + direct-global A-fragment reads regressed
//    (mfma 161->193 us). Direct-global A-reads dead in BOTH layouts (R7, R17).
//  * Register budget: 64 VGPR + 64 acc AGPR = 128 = exactly the 4-waves/SIMD
//    boundary. Do NOT add any live VGPR (no prefetch arrays, no hoisting).
//  * Status: latency-bound plateau at the register-occupancy ceiling; memory
//    floor ~70 us, both pipes <40%. All register-neutral, quarantine-safe,
//    layout-preserving levers have been measured; remaining ideas regressed.

constexpr int E_DIM = 2048;
constexpr int G_DIM = 32;
constexpr int D_DIM = 128;
constexpr float LN_EPS = 1e-3f;

constexpr int ROWS1 = 4;     // rows per block, gather part of prep
constexpr int BM    = 128;   // rows per block, compute pass (4 waves x 32 rows)
constexpr int AW    = 136;   // strip row stride in shorts (272 B: b128-aligned)
constexpr int WPREP_BLOCKS = 512;

typedef float f32x4  __attribute__((ext_vector_type(4)));
typedef short bf16x8 __attribute__((ext_vector_type(8)));

__device__ __forceinline__ short f2bf(float f) {   // RNE float->bf16 (finite inputs)
    uint32_t u = __builtin_bit_cast(uint32_t, f);
    uint32_t r = (u + 0x7fffu + ((u >> 16) & 1u)) >> 16;
    return (short)r;
}
__device__ __forceinline__ float bf2f(short s) {
    uint32_t u = ((uint32_t)(uint16_t)s) << 16;
    return __builtin_bit_cast(float, u);
}
// tanh-form GELU on HW exp2/rcp: max |diff vs exact| ~3e-3
__device__ __forceinline__ float gelu_fast(float x) {
    const float x2 = x * x;
    const float z  = 2.30220817f * x * fmaf(0.044715f, x2, 1.0f);
    const float e  = __builtin_amdgcn_exp2f(-z);
    return x * __builtin_amdgcn_rcpf(1.0f + e);
}

// ---------------- kernel 1: fused wprep + gather ----------------
template<bool WS>
__global__ __launch_bounds__(256) void ssb_prep_kernel(
    const float* __restrict__ x,
    const int*   __restrict__ idx,
    const float* __restrict__ W,
    short* __restrict__ Wf,
    float* __restrict__ outF,      // used when !WS (fp32 gather into d_out)
    short* __restrict__ outH,      // used when WS  (bf16 gather into d_ws)
    int gatherBlocks)
{
    const int tid = threadIdx.x;

    if ((int)blockIdx.x >= gatherBlocks) {
        // ---- wprep: W[g][l][k][n] fp32 -> bf16 B-fragment layout ----
        // frag: ((gl*8+nt)*4+ks)*512 + lane*8 + j <=> W[ks*32+8*(lane>>4)+j][nt*16+(lane&15)]
        const int t    = (blockIdx.x - gatherBlocks) * 256 + tid;   // 0 .. 131071
        const int lane = t & 63;
        const int ks   = (t >> 6) & 3;
        const int nt   = (t >> 8) & 7;
        const int gl   = t >> 11;                          // 0..63 = g*2+l
        const float* Wl = W + (size_t)gl * D_DIM * D_DIM;
        const int n  = nt * 16 + (lane & 15);
        const int k0 = ks * 32 + ((lane >> 4) << 3);
        short* dst = Wf + (size_t)t * 8;
        #pragma unroll
        for (int j = 0; j < 8; ++j) dst[j] = f2bf(Wl[(size_t)(k0 + j) * D_DIM + n]);
        return;
    }

    // ---- gather: x rows staged in LDS, all 32 groups emitted ----
    __shared__ float sX[ROWS1][E_DIM];     // 32 KB
    const int row0 = blockIdx.x * ROWS1;

    const int4 iv0 = *(const int4*)(idx + (0 * 256 + tid) * 4);
    const int4 iv1 = *(const int4*)(idx + (1 * 256 + tid) * 4);
    const int4 iv2 = *(const int4*)(idx + (2 * 256 + tid) * 4);
    const int4 iv3 = *(const int4*)(idx + (3 * 256 + tid) * 4);

    #pragma unroll
    for (int r = 0; r < ROWS1; ++r) {
        const float4* src = (const float4*)(x + (size_t)(row0 + r) * E_DIM);
        float4* dst = (float4*)sX[r];
        dst[tid]       = src[tid];
        dst[tid + 256] = src[tid + 256];
    }
    __syncthreads();

    #pragma unroll
    for (int r = 0; r < ROWS1; ++r) {
        const size_t base = (size_t)(row0 + r) * G_DIM * D_DIM;
        #pragma unroll
        for (int t = 0; t < 4; ++t) {
            const int4 iv = (t == 0) ? iv0 : (t == 1) ? iv1 : (t == 2) ? iv2 : iv3;
            const int j = (t * 256 + tid) * 4;
            const float v0 = sX[r][iv.x], v1 = sX[r][iv.y];
            const float v2 = sX[r][iv.z], v3 = sX[r][iv.w];
            if (WS) {
                short4 v; v.x = f2bf(v0); v.y = f2bf(v1); v.z = f2bf(v2); v.w = f2bf(v3);
                *(short4*)(outH + base + j) = v;
            } else {
                *(float4*)(outF + base + j) = make_float4(v0, v1, v2, v3);
            }
        }
    }
}

// ---------------- kernel 2: barrier-free MFMA, 32 rows/wave ----------------
template<bool WS>
__global__ __launch_bounds__(256, 4) void ssb_mfma_kernel(
    const short* __restrict__ Wf,
    const short* __restrict__ actH,    // WS: bf16 gathered [B][G][D]
    const float* __restrict__ bias,
    const float* __restrict__ gamma,
    const float* __restrict__ beta,
    float* __restrict__ out)
{
    __shared__ __align__(16) short sAct[4][32 * AW];   // 34.8 KB, wave-private strips

    const int g    = blockIdx.y;
    const int tid  = threadIdx.x;
    const int lane = tid & 63;
    const int wv   = tid >> 6;
    const int q    = lane >> 4;          // quarter 0..3
    const int c16  = lane & 15;
    const size_t rbase = (size_t)blockIdx.x * BM + wv * 32;   // wave's first row
    const size_t rowE  = (size_t)G_DIM * D_DIM;               // 4096 elems per batch row

    short* strip = sAct[wv];

    // ---- phase 0: load own 32-row strip into LDS as bf16 (quarter q loads rows 8q..8q+7) ----
    #pragma unroll
    for (int i = 0; i < 8; ++i) {
        const int rl = 8 * q + i;
        const size_t off = ((rbase + rl) * G_DIM + g) * D_DIM + 8 * c16;
        bf16x8 p;
        if (WS) {
            p = *(const bf16x8*)(actH + off);
        } else {
            const float4* src = (const float4*)(out + off);
            const float4 a0 = src[0], a1 = src[1];
            p[0] = f2bf(a0.x); p[1] = f2bf(a0.y); p[2] = f2bf(a0.z); p[3] = f2bf(a0.w);
            p[4] = f2bf(a1.x); p[5] = f2bf(a1.y); p[6] = f2bf(a1.z); p[7] = f2bf(a1.w);
        }
        *(bf16x8*)(strip + rl * AW + 8 * c16) = p;
    }

    const short* Wg0 = Wf + (size_t)(g * 2 + 0) * (D_DIM * D_DIM);
    const short* Wg1 = Wf + (size_t)(g * 2 + 1) * (D_DIM * D_DIM);

    f32x4 acc0[8], acc1[8];

    // ---- layer 0 (acc zero-init; bias added in GELU writeback) ----
    #pragma unroll
    for (int nt = 0; nt < 8; ++nt) { acc0[nt] = (f32x4){0,0,0,0}; acc1[nt] = (f32x4){0,0,0,0}; }
    __builtin_amdgcn_s_setprio(1);
    #pragma unroll
    for (int ks = 0; ks < 4; ++ks) {
        const bf16x8 a0 = *(const bf16x8*)(strip + (     c16) * AW + ks * 32 + q * 8);
        const bf16x8 a1 = *(const bf16x8*)(strip + (16 + c16) * AW + ks * 32 + q * 8);
        #pragma unroll
        for (int nt = 0; nt < 8; ++nt) {
            const bf16x8 bfr = *(const bf16x8*)(Wg0 + (nt * 4 + ks) * 512 + lane * 8);
            acc0[nt] = __builtin_amdgcn_mfma_f32_16x16x32_bf16(a0, bfr, acc0[nt], 0, 0, 0);
            acc1[nt] = __builtin_amdgcn_mfma_f32_16x16x32_bf16(a1, bfr, acc1[nt], 0, 0, 0);
        }
    }
    __builtin_amdgcn_s_setprio(0);

    // ---- GELU(acc + b0) -> own strip (wave-private, no barrier) ----
    {
        const float* bl0 = bias + (g * 2 + 0) * D_DIM;
        #pragma unroll
        for (int nt = 0; nt < 8; ++nt) {
            const float b0 = bl0[nt * 16 + c16];
            #pragma unroll
            for (int j = 0; j < 4; ++j) {
                strip[(     4 * q + j) * AW + nt * 16 + c16] = f2bf(gelu_fast(acc0[nt][j] + b0));
                strip[(16 + 4 * q + j) * AW + nt * 16 + c16] = f2bf(gelu_fast(acc1[nt][j] + b0));
            }
        }
    }

    // ---- layer 1 (acc zero-init; bias added in epilogue) ----
    #pragma unroll
    for (int nt = 0; nt < 8; ++nt) { acc0[nt] = (f32x4){0,0,0,0}; acc1[nt] = (f32x4){0,0,0,0}; }
    __builtin_amdgcn_s_setprio(1);
    #pragma unroll
    for (int ks = 0; ks < 4; ++ks) {
        const bf16x8 a0 = *(const bf16x8*)(strip + (     c16) * AW + ks * 32 + q * 8);
        const bf16x8 a1 = *(const bf16x8*)(strip + (16 + c16) * AW + ks * 32 + q * 8);
        #pragma unroll
        for (int nt = 0; nt < 8; ++nt) {
            const bf16x8 bfr = *(const bf16x8*)(Wg1 + (nt * 4 + ks) * 512 + lane * 8);
            acc0[nt] = __builtin_amdgcn_mfma_f32_16x16x32_bf16(a0, bfr, acc0[nt], 0, 0, 0);
            acc1[nt] = __builtin_amdgcn_mfma_f32_16x16x32_bf16(a1, bfr, acc1[nt], 0, 0, 0);
        }
    }
    __builtin_amdgcn_s_setprio(0);

    // ---- epilogue (per m-tile; scalar layout QUARANTINED) ----
    const float* bl1 = bias + (g * 2 + 1) * D_DIM;
    float b1[8], gm[8], bt[8];
    #pragma unroll
    for (int nt = 0; nt < 8; ++nt) {
        b1[nt] = bl1[nt * 16 + c16];
        gm[nt] = gamma[g * D_DIM + nt * 16 + c16];
        bt[nt] = beta [g * D_DIM + nt * 16 + c16];
    }

    auto epilogue = [&](f32x4* acc, int mt) {
        const size_t r0 = (rbase + mt * 16 + 4 * q) * rowE + (size_t)g * D_DIM + c16;
        const short* rp = actH + r0;   // WS residual base (row stride rowE)
        const float* fp = out  + r0;   // !WS residual base
        float s[4] = {0, 0, 0, 0}, s2[4] = {0, 0, 0, 0};
        #pragma unroll
        for (int j = 0; j < 4; ++j) {
            #pragma unroll
            for (int nt = 0; nt < 8; ++nt) {
                const float res = WS ? bf2f(rp[j * 4096 + nt * 16]) : fp[j * 4096 + nt * 16];
                const float v = gelu_fast(acc[nt][j] + b1[nt]) + res;
                acc[nt][j] = v;
                s[j] += v; s2[j] += v * v;
            }
        }
        float mu[4], rs[4];
        #pragma unroll
        for (int j = 0; j < 4; ++j) {
            #pragma unroll
            for (int m = 8; m >= 1; m >>= 1) {
                s[j]  += __shfl_xor(s[j],  m, 64);
                s2[j] += __shfl_xor(s2[j], m, 64);
            }
            mu[j] = s[j] * (1.0f / 128.0f);
            const float var = fmaxf(s2[j] * (1.0f / 128.0f) - mu[j] * mu[j], 0.f);
            rs[j] = rsqrtf(var + LN_EPS);
        }
        float* op = out + r0;
        #pragma unroll
        for (int j = 0; j < 4; ++j) {
            #pragma unroll
            for (int nt = 0; nt < 8; ++nt) {
                op[j * 4096 + nt * 16] = (acc[nt][j] - mu[j]) * rs[j] * gm[nt] + bt[nt];
            }
        }
    };
    epilogue(acc0, 0);
    epilogue(acc1, 1);
}

extern "C" void kernel_launch(void* const* d_in, const int* in_sizes, int n_in,
                              void* d_out, int out_size, void* d_ws, size_t ws_size,
                              hipStream_t stream) {
    const float* x     = (const float*)d_in[0];
    const int*   idx   = (const int*)d_in[1];
    const float* W     = (const float*)d_in[2];
    const float* b     = (const float*)d_in[3];
    const float* gamma = (const float*)d_in[4];
    const float* beta  = (const float*)d_in[5];
    float* out = (float*)d_out;
    short* Wf  = (short*)d_ws;                       // 2 MB bf16 fragment-layout W

    const int B = in_sizes[0] / E_DIM;               // 16384
    const size_t wfElems  = (size_t)G_DIM * 2 * D_DIM * D_DIM;       // 1 Mi shorts
    const size_t actElems = (size_t)B * G_DIM * D_DIM;               // 64 Mi shorts
    const bool useWs = ws_size >= (wfElems + actElems) * sizeof(short);
    short* actH = Wf + wfElems;

    const int gatherBlocks = B / ROWS1;              // 4096

    if (useWs) {
        ssb_prep_kernel<true ><<<dim3(gatherBlocks + WPREP_BLOCKS), 256, 0, stream>>>(
            x, idx, W, Wf, out, actH, gatherBlocks);
        ssb_mfma_kernel<true ><<<dim3(B / BM, G_DIM), 256, 0, stream>>>(
            Wf, actH, b, gamma, beta, out);
    } else {
        ssb_prep_kernel<false><<<dim3(gatherBlocks + WPREP_BLOCKS), 256, 0, stream>>>(
            x, idx, W, Wf, out, actH, gatherBlocks);
        ssb_mfma_kernel<false><<<dim3(B / BM, G_DIM), 256, 0, stream>>>(
            Wf, actH, b, gamma, beta, out);
    }
}